// Round 2
// baseline (4432.321 us; speedup 1.0000x reference)
//
#include <hip/hip_runtime.h>
#include <hip/hip_bf16.h>
#include <stdint.h>

#define H_  10
#define B_  16384
#define F_  4
#define D_  2048
#define C_  2

typedef __attribute__((ext_vector_type(8))) short  short8;
typedef __attribute__((ext_vector_type(4))) float  floatx4;

typedef const uint32_t __attribute__((address_space(1))) gu32;
typedef uint32_t       __attribute__((address_space(3))) lu32;

__device__ __forceinline__ void async16(const void* g, void* l) {
    __builtin_amdgcn_global_load_lds((gu32*)g, (lu32*)l, 16, 0, 0);
}

__device__ __forceinline__ short8 bc8(uint4 v) { return __builtin_bit_cast(short8, v); }

// relu + round-half-up bf16 pack (hot path, proven numerics)
__device__ __forceinline__ uint32_t packbf(float a, float b) {
    a = fmaxf(a, 0.f); b = fmaxf(b, 0.f);
    const uint32_t ax = __builtin_bit_cast(uint32_t, a) + 0x8000u;
    const uint32_t bx = __builtin_bit_cast(uint32_t, b) + 0x8000u;
    return (ax >> 16) | (bx & 0xFFFF0000u);
}

// full-precision RNE pack (convert kernel only)
__device__ __forceinline__ uint32_t f2bf(float f) {
    union { float f; uint32_t u; } a; a.f = f;
    uint32_t u = a.u;
    u += 0x7FFF + ((u >> 16) & 1);
    return u >> 16;
}
__device__ __forceinline__ uint32_t pack2bf(float a, float b) {
    return f2bf(a) | (f2bf(b) << 16);
}

// ---------------------------------------------------------------------------
// ws layout (bytes) — total 237,502,464:
//   0          : Bc    bf16 [H][4096][2048] (n-major, k-contig; n<2048 = W21,
//                                            n>=2048 = W22)      167,772,160
//   167772160  : acc31 f32 [H][B_][C_]                             1,310,720
//   169082880  : acc32 f32 [H][B_][C_]                             1,310,720
//   170393600  : h1t   bf16 [B_][2048]  (per-head, reused)        67,108,864
// ---------------------------------------------------------------------------

__global__ __launch_bounds__(256) void k_convert(
    const float* __restrict__ W21, const float* __restrict__ W22,
    uint16_t* __restrict__ Bc)
{
    __shared__ float tile[64][65];
    const int z = blockIdx.z;
    const int h = z % H_;
    const float* src = (z < H_ ? W21 : W22) + (size_t)h * D_ * D_;
    uint16_t*   dst  = Bc + (size_t)h * 2 * D_ * D_ + (z < H_ ? 0 : (size_t)D_ * D_);
    const int k0 = blockIdx.x * 64, n0 = blockIdx.y * 64;
    const int t = threadIdx.x;

    const int c4 = (t & 15) * 4;
    const int rb = (t >> 4) * 4;
#pragma unroll
    for (int i = 0; i < 4; i++) {
        const float4 v = *(const float4*)(src + (size_t)(k0 + rb + i) * D_ + n0 + c4);
        tile[rb + i][c4 + 0] = v.x; tile[rb + i][c4 + 1] = v.y;
        tile[rb + i][c4 + 2] = v.z; tile[rb + i][c4 + 3] = v.w;
    }
    __syncthreads();
    const int n = t >> 2;
    const int cb = (t & 3) * 2;
#pragma unroll
    for (int j = 0; j < 2; j++) {
        const int kk = (cb + j) * 8;
        uint32_t pk[4];
#pragma unroll
        for (int e = 0; e < 4; e++)
            pk[e] = pack2bf(tile[kk + 2 * e][n], tile[kk + 2 * e + 1][n]);
        *(uint4*)(dst + (size_t)(n0 + n) * D_ + k0 + kk) = make_uint4(pk[0], pk[1], pk[2], pk[3]);
    }
}

__global__ __launch_bounds__(256) void k_zero(uint4* p, int n4) {
    const int i = blockIdx.x * 256 + threadIdx.x;
    if (i < n4) p[i] = make_uint4(0u, 0u, 0u, 0u);
}

// ---------------------------------------------------------------------------
// h1 = relu(x @ W1[h] + b1[h])  -> bf16 [B_][2048], row-major k-contig
// ---------------------------------------------------------------------------
__global__ __launch_bounds__(256) void k_h1(
    const float* __restrict__ x, const float* __restrict__ W1,
    const float* __restrict__ b1, uint16_t* __restrict__ h1t, int h)
{
    const int t = threadIdx.x;
    const int kc = t & 127;            // 16-wide k chunk
    const int rh = t >> 7;             // 0,1
    const int k0 = kc * 16;
    const float* W1h = W1 + (size_t)h * F_ * D_;
    float w[4][16], bb[16];
#pragma unroll
    for (int f = 0; f < 4; f++)
#pragma unroll
        for (int j = 0; j < 16; j += 4) {
            const float4 v = *(const float4*)(W1h + f * D_ + k0 + j);
            w[f][j] = v.x; w[f][j+1] = v.y; w[f][j+2] = v.z; w[f][j+3] = v.w;
        }
#pragma unroll
    for (int j = 0; j < 16; j += 4) {
        const float4 v = *(const float4*)(b1 + (size_t)h * D_ + k0 + j);
        bb[j] = v.x; bb[j+1] = v.y; bb[j+2] = v.z; bb[j+3] = v.w;
    }
    const int rowBase = blockIdx.x * 16 + rh * 8;
#pragma unroll
    for (int rr = 0; rr < 8; rr++) {
        const int row = rowBase + rr;
        const float4 xv = *(const float4*)(x + (size_t)row * 4);
        uint32_t pk[8];
#pragma unroll
        for (int j = 0; j < 16; j += 2) {
            float aa = fmaf(xv.x, w[0][j], bb[j]);
            aa = fmaf(xv.y, w[1][j], aa);
            aa = fmaf(xv.z, w[2][j], aa);
            aa = fmaf(xv.w, w[3][j], aa);
            float bv = fmaf(xv.x, w[0][j+1], bb[j+1]);
            bv = fmaf(xv.y, w[1][j+1], bv);
            bv = fmaf(xv.z, w[2][j+1], bv);
            bv = fmaf(xv.w, w[3][j+1], bv);
            pk[j >> 1] = packbf(aa, bv);
        }
        uint16_t* d = h1t + (size_t)row * D_ + k0;
        *(uint4*)d       = make_uint4(pk[0], pk[1], pk[2], pk[3]);
        *(uint4*)(d + 8) = make_uint4(pk[4], pk[5], pk[6], pk[7]);
    }
}

// ---------------------------------------------------------------------------
// 256x256 tile, BK=64, 8 waves (2M x 4N), double-buffered LDS (128 KB).
// Software-pipelined 4-phase K loop: each phase issues the ds_reads for the
// NEXT phase's MFMAs (balanced 8/4/4/8) and waits with COUNTED lgkmcnt, so
// LDS drain overlaps the MFMA clusters. A and B staged 2 K-tiles ahead;
// single counted vmcnt(4) per K-tile (after M2's cluster). 4 barriers/K-tile.
// Quadrant order: M1=(mg0,ng0) M2=(mg1,ng0) M3=(mg0,ng1) M4=(mg1,ng1) so each
// fragment dies one phase before its next-tile replacement is read in place.
// LDS layout (uint4 units): unit = row*8 + (kchunk ^ (row&7))  [0-conflict]
// ---------------------------------------------------------------------------
__global__ __launch_bounds__(512, 2) void k_gemm(
    const uint16_t* __restrict__ h1t, const uint16_t* __restrict__ Bcw,
    const float* __restrict__ b21, const float* __restrict__ b22,
    const float* __restrict__ W31, const float* __restrict__ W32,
    float* __restrict__ acc31, float* __restrict__ acc32, int h)
{
    extern __shared__ uint4 smem[];
    uint4* Asl = smem;            // [2][2048] uint4 = 64 KB
    uint4* Bsl = smem + 4096;     // [2][2048] uint4 = 64 KB

    // bijective XCD swizzle: 1024 wgs -> 128-contiguous chunk per XCD
    const int bid = blockIdx.x;
    const int wg  = (bid & 7) * 128 + (bid >> 3);
    const int mBase = (wg & 63) * 256;
    const int nBase = (wg >> 6) * 256;      // in concat [0,4096)

    const int t = threadIdx.x;
    const int lane = t & 63, wid = t >> 6;
    const int c15 = lane & 15, q = lane >> 4;
    const int wm = wid >> 2, wn = wid & 3;

    // staging geometry: lane l stages row (i*64 + wid*8 + (l>>3)), chunk (l&7)^(l>>3)
    const int srow   = lane >> 3;
    const int schunk = (lane & 7) ^ srow;
    const int sldA   = wid * 64;            // uint4 units (lane offset added by HW)

    const uint16_t* Ag = h1t + (size_t)(mBase + wid * 8 + srow) * D_ + schunk * 8;
    const uint16_t* Bg = Bcw + (size_t)h * (4096 * (size_t)D_)
                             + (size_t)(nBase + wid * 8 + srow) * D_ + schunk * 8;

    auto stageA = [&](int buf, int kt) {
#pragma unroll
        for (int i = 0; i < 4; i++)
            async16(Ag + (size_t)(i * 64) * D_ + kt,
                    Asl + buf * 2048 + i * 512 + sldA);
    };
    auto stageB = [&](int buf, int kt) {
#pragma unroll
        for (int i = 0; i < 4; i++)
            async16(Bg + (size_t)(i * 64) * D_ + kt,
                    Bsl + buf * 2048 + i * 512 + sldA);
    };

    // ds_read geometry
    const int axor  = c15 & 7;
    const int ck0   = q ^ axor;
    const int ck1   = (q + 4) ^ axor;
    const int abase = (wm * 128 + c15) * 8;
    const int bbase = (wn * 64 + c15) * 8;

    floatx4 acc[8][4];
    const floatx4 z4 = {0.f, 0.f, 0.f, 0.f};
#pragma unroll
    for (int mi = 0; mi < 8; mi++)
#pragma unroll
        for (int ni = 0; ni < 4; ni++) acc[mi][ni] = z4;

    short8 a0[4][2], a1[4][2], b0[2][2], b1[2][2];

    // ---- prologue: stage tiles 0,1 (A+B); wait tile 0; read a0,b0 of tile 0
    stageA(0, 0);   stageB(0, 0);
    stageA(1, 64);  stageB(1, 64);
    asm volatile("s_waitcnt vmcnt(8)" ::: "memory");   // tile 0 landed; tile 1 in flight
    __builtin_amdgcn_sched_barrier(0);
    __builtin_amdgcn_s_barrier();
#pragma unroll
    for (int mi = 0; mi < 4; mi++) {
        a0[mi][0] = bc8(Asl[abase + mi * 128 + ck0]);
        a0[mi][1] = bc8(Asl[abase + mi * 128 + ck1]);
    }
#pragma unroll
    for (int ni = 0; ni < 2; ni++) {
        b0[ni][0] = bc8(Bsl[bbase + ni * 128 + ck0]);
        b0[ni][1] = bc8(Bsl[bbase + ni * 128 + ck1]);
    }

    for (int tt = 0; tt < 32; ++tt) {
        const int cur = tt & 1, nxt = cur ^ 1;
        const uint4* Ac = Asl + cur * 2048;
        const uint4* Bb = Bsl + cur * 2048;
        const uint4* An = Asl + nxt * 2048;
        const uint4* Bn = Bsl + nxt * 2048;
        const int kt2 = (tt < 30 ? tt + 2 : 31) * 64;   // tile t+2 (clamped tail)

        // ---- M1: read a1(t) [8]; MFMA (mg0,ng0) = a0 x b0
#pragma unroll
        for (int mi = 0; mi < 4; mi++) {
            a1[mi][0] = bc8(Ac[abase + (mi + 4) * 128 + ck0]);
            a1[mi][1] = bc8(Ac[abase + (mi + 4) * 128 + ck1]);
        }
        asm volatile("s_waitcnt lgkmcnt(8)" ::: "memory");  // a0,b0 ready; a1 in flight
        __builtin_amdgcn_sched_barrier(0);
        __builtin_amdgcn_s_setprio(1);
#pragma unroll
        for (int mi = 0; mi < 4; mi++)
#pragma unroll
            for (int ni = 0; ni < 2; ni++) {
                acc[mi][ni] = __builtin_amdgcn_mfma_f32_16x16x32_bf16(a0[mi][0], b0[ni][0], acc[mi][ni], 0, 0, 0);
                acc[mi][ni] = __builtin_amdgcn_mfma_f32_16x16x32_bf16(a0[mi][1], b0[ni][1], acc[mi][ni], 0, 0, 0);
            }
        __builtin_amdgcn_s_setprio(0);
        __builtin_amdgcn_s_barrier();

        // ---- M2: stage A(t+2)->Asl[cur]; read b1(t) [4]; MFMA (mg1,ng0) = a1 x b0
        stageA(cur, kt2);
#pragma unroll
        for (int ni = 0; ni < 2; ni++) {
            b1[ni][0] = bc8(Bb[bbase + (ni + 2) * 128 + ck0]);
            b1[ni][1] = bc8(Bb[bbase + (ni + 2) * 128 + ck1]);
        }
        asm volatile("s_waitcnt lgkmcnt(4)" ::: "memory");  // a1 ready; b1 in flight
        __builtin_amdgcn_sched_barrier(0);
        __builtin_amdgcn_s_setprio(1);
#pragma unroll
        for (int mi = 0; mi < 4; mi++)
#pragma unroll
            for (int ni = 0; ni < 2; ni++) {
                acc[mi + 4][ni] = __builtin_amdgcn_mfma_f32_16x16x32_bf16(a1[mi][0], b0[ni][0], acc[mi + 4][ni], 0, 0, 0);
                acc[mi + 4][ni] = __builtin_amdgcn_mfma_f32_16x16x32_bf16(a1[mi][1], b0[ni][1], acc[mi + 4][ni], 0, 0, 0);
            }
        __builtin_amdgcn_s_setprio(0);
        // counted vmcnt: outstanding = A(t+1),B(t+1),A(t+2) = 12 -> wait tile t+1 landed
        asm volatile("s_waitcnt vmcnt(4)" ::: "memory");
        __builtin_amdgcn_sched_barrier(0);
        __builtin_amdgcn_s_barrier();

        // ---- M3: stage B(t+2)->Bsl[cur]; read b0(t+1) [4] from Bsl[nxt]; MFMA (mg0,ng1) = a0 x b1
        stageB(cur, kt2);
#pragma unroll
        for (int ni = 0; ni < 2; ni++) {
            b0[ni][0] = bc8(Bn[bbase + ni * 128 + ck0]);
            b0[ni][1] = bc8(Bn[bbase + ni * 128 + ck1]);
        }
        asm volatile("s_waitcnt lgkmcnt(4)" ::: "memory");  // b1 ready; b0(next) in flight
        __builtin_amdgcn_sched_barrier(0);
        __builtin_amdgcn_s_setprio(1);
#pragma unroll
        for (int mi = 0; mi < 4; mi++)
#pragma unroll
            for (int ni = 0; ni < 2; ni++) {
                acc[mi][ni + 2] = __builtin_amdgcn_mfma_f32_16x16x32_bf16(a0[mi][0], b1[ni][0], acc[mi][ni + 2], 0, 0, 0);
                acc[mi][ni + 2] = __builtin_amdgcn_mfma_f32_16x16x32_bf16(a0[mi][1], b1[ni][1], acc[mi][ni + 2], 0, 0, 0);
            }
        __builtin_amdgcn_s_setprio(0);
        __builtin_amdgcn_s_barrier();

        // ---- M4: read a0(t+1) [8] from Asl[nxt]; MFMA (mg1,ng1) = a1 x b1
#pragma unroll
        for (int mi = 0; mi < 4; mi++) {
            a0[mi][0] = bc8(An[abase + mi * 128 + ck0]);
            a0[mi][1] = bc8(An[abase + mi * 128 + ck1]);
        }
        asm volatile("s_waitcnt lgkmcnt(12)" ::: "memory"); // b1 long done; b0n+a0n in flight
        __builtin_amdgcn_sched_barrier(0);
        __builtin_amdgcn_s_setprio(1);
#pragma unroll
        for (int mi = 0; mi < 4; mi++)
#pragma unroll
            for (int ni = 0; ni < 2; ni++) {
                acc[mi + 4][ni + 2] = __builtin_amdgcn_mfma_f32_16x16x32_bf16(a1[mi][0], b1[ni][0], acc[mi + 4][ni + 2], 0, 0, 0);
                acc[mi + 4][ni + 2] = __builtin_amdgcn_mfma_f32_16x16x32_bf16(a1[mi][1], b1[ni][1], acc[mi + 4][ni + 2], 0, 0, 0);
            }
        __builtin_amdgcn_s_setprio(0);
        __builtin_amdgcn_s_barrier();
    }

    // ---- Epilogue: bias + relu + (.)@W3[half] reduce over n, shuffle, atomics
    const int p    = nBase >> 11;          // 0: W21/W31 path, 1: W22/W32 path
    const int nloc = nBase & 2047;
    const float* b2p = (p ? b22 : b21) + (size_t)h * D_;
    const float* W3p = (p ? W32 : W31) + (size_t)h * D_ * C_;
    float* ab = (p ? acc32 : acc31) + (size_t)h * B_ * C_;

    float w3x[4], w3y[4], bs[4];
#pragma unroll
    for (int ni = 0; ni < 4; ni++) {
        const int e = nloc + wn * 64 + ni * 16 + c15;
        bs[ni] = b2p[e];
        const float2 w2 = *(const float2*)(W3p + e * 2);
        w3x[ni] = w2.x; w3y[ni] = w2.y;
    }
#pragma unroll
    for (int mi = 0; mi < 8; mi++) {
        float s0[4], s1[4];
#pragma unroll
        for (int r = 0; r < 4; r++) {
            float t0 = 0.f, t1 = 0.f;
#pragma unroll
            for (int ni = 0; ni < 4; ni++) {
                float v = fmaxf(acc[mi][ni][r] + bs[ni], 0.f);
                t0 = fmaf(v, w3x[ni], t0);
                t1 = fmaf(v, w3y[ni], t1);
            }
            s0[r] = t0; s1[r] = t1;
        }
#pragma unroll
        for (int off = 1; off < 16; off <<= 1)
#pragma unroll
            for (int r = 0; r < 4; r++) {
                s0[r] += __shfl_xor(s0[r], off, 64);
                s1[r] += __shfl_xor(s1[r], off, 64);
            }
        if (c15 == 0) {
#pragma unroll
            for (int r = 0; r < 4; r++) {
                const int row = mBase + wm * 128 + mi * 16 + q * 4 + r;
                atomicAdd(&ab[row * C_ + 0], s0[r]);
                atomicAdd(&ab[row * C_ + 1], s1[r]);
            }
        }
    }
}

// ---------------------------------------------------------------------------
// Finalize: biases, sigmoid head, CBF-QP correction, softmax-weighted mix
// ---------------------------------------------------------------------------
__global__ __launch_bounds__(256) void k_final(
    const float* __restrict__ x,
    const float* __restrict__ acc31, const float* __restrict__ acc32,
    const float* __restrict__ b31, const float* __restrict__ b32,
    const float* __restrict__ wt, const float* __restrict__ mean,
    const float* __restrict__ stdv, float* __restrict__ out)
{
    const int b = blockIdx.x * 256 + threadIdx.x;
    const float4 xb = *(const float4*)(x + (size_t)b * 4);
    const float px = xb.x * stdv[0] + mean[0];
    const float py = xb.y * stdv[1] + mean[1];
    const float th = xb.z * stdv[2] + mean[2];
    const float v  = xb.w * stdv[3] + mean[3];
    const float dx = px - 40.0f, dy = py - 15.0f;
    const float st = sinf(th), ct = cosf(th);
    const float barrier = dx * dx + dy * dy - 36.0f;
    const float bdot = 2.f * dx * v * ct + 2.f * dy * v * st;
    const float Lf2b = 2.f * v * v;
    const float G0 = -(-2.f * dx * v * st + 2.f * dy * v * ct);
    const float G1 = -(2.f * dx * ct + 2.f * dy * st);
    const float GG = G0 * G0 + G1 * G1;

    float we[H_];
    float wmax = wt[0];
    for (int h = 1; h < H_; h++) wmax = fmaxf(wmax, wt[h]);
    float wsum = 0.f;
    for (int h = 0; h < H_; h++) { we[h] = expf(wt[h] - wmax); wsum += we[h]; }

    float o0 = 0.f, o1 = 0.f;
#pragma unroll
    for (int h = 0; h < H_; h++) {
        const size_t idx = ((size_t)h * B_ + b) * 2;
        const float x310 = acc31[idx]     + b31[h * 2];
        const float x311 = acc31[idx + 1] + b31[h * 2 + 1];
        const float z0 = acc32[idx]     + b32[h * 2];
        const float z1 = acc32[idx + 1] + b32[h * 2 + 1];
        const float x320 = 4.f / (1.f + expf(-z0));
        const float x321 = 4.f / (1.f + expf(-z1));
        const float hr = Lf2b + (x320 + x321) * bdot + x320 * x321 * barrier;
        const float Gu = G0 * x310 + G1 * x311;
        const float lam = fmaxf(Gu - hr, 0.f) / GG;
        o0 += we[h] * (x310 - lam * G0);
        o1 += we[h] * (x311 - lam * G1);
    }
    out[b * 2]     = o0 / wsum;
    out[b * 2 + 1] = o1 / wsum;
}

extern "C" void kernel_launch(void* const* d_in, const int* in_sizes, int n_in,
                              void* d_out, int out_size, void* d_ws, size_t ws_size,
                              hipStream_t stream)
{
    const float* x    = (const float*)d_in[0];
    const float* W1   = (const float*)d_in[1];
    const float* b1   = (const float*)d_in[2];
    const float* W21  = (const float*)d_in[3];
    const float* b21  = (const float*)d_in[4];
    const float* W22  = (const float*)d_in[5];
    const float* b22  = (const float*)d_in[6];
    const float* W31  = (const float*)d_in[7];
    const float* b31  = (const float*)d_in[8];
    const float* W32  = (const float*)d_in[9];
    const float* b32  = (const float*)d_in[10];
    const float* wt   = (const float*)d_in[11];
    const float* mean = (const float*)d_in[12];
    const float* stdv = (const float*)d_in[13];
    float* out = (float*)d_out;

    char* ws = (char*)d_ws;
    uint16_t* Bc   = (uint16_t*)(ws);
    float* acc31   = (float*)(ws + 167772160);
    float* acc32   = (float*)(ws + 169082880);
    uint16_t* h1t  = (uint16_t*)(ws + 170393600);

    static bool attr_done = false;
    if (!attr_done) {
        hipFuncSetAttribute(reinterpret_cast<const void*>(k_gemm),
                            hipFuncAttributeMaxDynamicSharedMemorySize, 131072);
        attr_done = true;
    }

    k_convert<<<dim3(32, 32, 20), 256, 0, stream>>>(W21, W22, Bc);
    k_zero<<<dim3(640), 256, 0, stream>>>((uint4*)acc31, 163840);
    for (int h = 0; h < H_; ++h) {
        k_h1<<<dim3(1024), 256, 0, stream>>>(x, W1, b1, h1t, h);
        k_gemm<<<dim3(1024), 512, 131072, stream>>>(h1t, Bc, b21, b22, W31, W32,
                                                    acc31, acc32, h);
    }
    k_final<<<dim3(64), 256, 0, stream>>>(x, acc31, acc32, b31, b32, wt, mean, stdv, out);
}

// Round 3
// 3342.205 us; speedup vs baseline: 1.3262x; 1.3262x over previous
//
#include <hip/hip_runtime.h>
#include <hip/hip_bf16.h>
#include <stdint.h>

#define H_  10
#define B_  16384
#define F_  4
#define D_  2048
#define C_  2

typedef __attribute__((ext_vector_type(8)))  short  short8;
typedef __attribute__((ext_vector_type(16))) float  floatx16;

typedef const uint32_t __attribute__((address_space(1))) gu32;
typedef uint32_t       __attribute__((address_space(3))) lu32;

__device__ __forceinline__ void async16(const void* g, void* l) {
    __builtin_amdgcn_global_load_lds((gu32*)g, (lu32*)l, 16, 0, 0);
}

__device__ __forceinline__ short8 bc8(uint4 v) { return __builtin_bit_cast(short8, v); }

// relu + round-half-up bf16 pack (hot path, proven numerics)
__device__ __forceinline__ uint32_t packbf(float a, float b) {
    a = fmaxf(a, 0.f); b = fmaxf(b, 0.f);
    const uint32_t ax = __builtin_bit_cast(uint32_t, a) + 0x8000u;
    const uint32_t bx = __builtin_bit_cast(uint32_t, b) + 0x8000u;
    return (ax >> 16) | (bx & 0xFFFF0000u);
}

// full-precision RNE pack (convert kernel only)
__device__ __forceinline__ uint32_t f2bf(float f) {
    union { float f; uint32_t u; } a; a.f = f;
    uint32_t u = a.u;
    u += 0x7FFF + ((u >> 16) & 1);
    return u >> 16;
}
__device__ __forceinline__ uint32_t pack2bf(float a, float b) {
    return f2bf(a) | (f2bf(b) << 16);
}

// ---------------------------------------------------------------------------
// ws layout (bytes) — total 237,502,464 (proven in-budget R1/R2):
//   0          : Bc    bf16 [H][4096][2048] (n-major, k-contig; n<2048 = W21,
//                                            n>=2048 = W22)      167,772,160
//   167772160  : acc31 f32 [H][B_][C_]                             1,310,720
//   169082880  : acc32 f32 [H][B_][C_]                             1,310,720
//   170393600  : h1t   bf16 [B_][2048]  (per-head, reused)        67,108,864
// ---------------------------------------------------------------------------

__global__ __launch_bounds__(256) void k_convert(
    const float* __restrict__ W21, const float* __restrict__ W22,
    uint16_t* __restrict__ Bc)
{
    __shared__ float tile[64][65];
    const int z = blockIdx.z;
    const int h = z % H_;
    const float* src = (z < H_ ? W21 : W22) + (size_t)h * D_ * D_;
    uint16_t*   dst  = Bc + (size_t)h * 2 * D_ * D_ + (z < H_ ? 0 : (size_t)D_ * D_);
    const int k0 = blockIdx.x * 64, n0 = blockIdx.y * 64;
    const int t = threadIdx.x;

    const int c4 = (t & 15) * 4;
    const int rb = (t >> 4) * 4;
#pragma unroll
    for (int i = 0; i < 4; i++) {
        const float4 v = *(const float4*)(src + (size_t)(k0 + rb + i) * D_ + n0 + c4);
        tile[rb + i][c4 + 0] = v.x; tile[rb + i][c4 + 1] = v.y;
        tile[rb + i][c4 + 2] = v.z; tile[rb + i][c4 + 3] = v.w;
    }
    __syncthreads();
    const int n = t >> 2;
    const int cb = (t & 3) * 2;
#pragma unroll
    for (int j = 0; j < 2; j++) {
        const int kk = (cb + j) * 8;
        uint32_t pk[4];
#pragma unroll
        for (int e = 0; e < 4; e++)
            pk[e] = pack2bf(tile[kk + 2 * e][n], tile[kk + 2 * e + 1][n]);
        *(uint4*)(dst + (size_t)(n0 + n) * D_ + k0 + kk) = make_uint4(pk[0], pk[1], pk[2], pk[3]);
    }
}

__global__ __launch_bounds__(256) void k_zero(uint4* p, int n4) {
    const int i = blockIdx.x * 256 + threadIdx.x;
    if (i < n4) p[i] = make_uint4(0u, 0u, 0u, 0u);
}

// ---------------------------------------------------------------------------
// h1 = relu(x @ W1[h] + b1[h])  -> bf16 [B_][2048], row-major k-contig
// ---------------------------------------------------------------------------
__global__ __launch_bounds__(256) void k_h1(
    const float* __restrict__ x, const float* __restrict__ W1,
    const float* __restrict__ b1, uint16_t* __restrict__ h1t, int h)
{
    const int t = threadIdx.x;
    const int kc = t & 127;            // 16-wide k chunk
    const int rh = t >> 7;             // 0,1
    const int k0 = kc * 16;
    const float* W1h = W1 + (size_t)h * F_ * D_;
    float w[4][16], bb[16];
#pragma unroll
    for (int f = 0; f < 4; f++)
#pragma unroll
        for (int j = 0; j < 16; j += 4) {
            const float4 v = *(const float4*)(W1h + f * D_ + k0 + j);
            w[f][j] = v.x; w[f][j+1] = v.y; w[f][j+2] = v.z; w[f][j+3] = v.w;
        }
#pragma unroll
    for (int j = 0; j < 16; j += 4) {
        const float4 v = *(const float4*)(b1 + (size_t)h * D_ + k0 + j);
        bb[j] = v.x; bb[j+1] = v.y; bb[j+2] = v.z; bb[j+3] = v.w;
    }
    const int rowBase = blockIdx.x * 16 + rh * 8;
#pragma unroll
    for (int rr = 0; rr < 8; rr++) {
        const int row = rowBase + rr;
        const float4 xv = *(const float4*)(x + (size_t)row * 4);
        uint32_t pk[8];
#pragma unroll
        for (int j = 0; j < 16; j += 2) {
            float aa = fmaf(xv.x, w[0][j], bb[j]);
            aa = fmaf(xv.y, w[1][j], aa);
            aa = fmaf(xv.z, w[2][j], aa);
            aa = fmaf(xv.w, w[3][j], aa);
            float bv = fmaf(xv.x, w[0][j+1], bb[j+1]);
            bv = fmaf(xv.y, w[1][j+1], bv);
            bv = fmaf(xv.z, w[2][j+1], bv);
            bv = fmaf(xv.w, w[3][j+1], bv);
            pk[j >> 1] = packbf(aa, bv);
        }
        uint16_t* d = h1t + (size_t)row * D_ + k0;
        *(uint4*)d       = make_uint4(pk[0], pk[1], pk[2], pk[3]);
        *(uint4*)(d + 8) = make_uint4(pk[4], pk[5], pk[6], pk[7]);
    }
}

// ---------------------------------------------------------------------------
// BM=128 x BN=256 tile, BK=64, 256 threads (4 waves, 1Mx4N), 48 KB LDS
// single-buffered -> 2 blocks/CU anti-phase overlap (R0's proven mechanism).
// MFMA: 32x32x16 bf16 (2382 TF ubench vs 2075 for 16x16x32; same LDS bytes).
// Per-wave output 128x64 = 4m x 2n frags of 32x32 (16 f32 acc regs each).
// LDS swizzle (uint4 units): unit(row,c) = row*8 + (c ^ (row&7))  [0-conflict]
// achieved by pre-swizzled global source + linear global_load_lds dest.
// Frag layouts (verified lane patterns): A row=l&31, k=(l>>5)*8+e;
// B col=l&31, k=(l>>5)*8+e; C col=l&31, row=(r&3)+8*(r>>2)+4*(l>>5).
// Epilogue: bias+relu+(.)@W3 reduce over n (32-lane shuffle), atomics.
// ---------------------------------------------------------------------------
__global__ __launch_bounds__(256, 2) void k_gemm(
    const uint16_t* __restrict__ h1t, const uint16_t* __restrict__ Bcw,
    const float* __restrict__ b21, const float* __restrict__ b22,
    const float* __restrict__ W31, const float* __restrict__ W32,
    float* __restrict__ acc31, float* __restrict__ acc32, int h)
{
    __shared__ uint4 smem[3072];     // A: [0,1024) units, B: [1024,3072)

    // XCD-contiguous M-slice: xcd owns m-tiles [xcd*16, xcd*16+16), sweeps n
    const int bid = blockIdx.x;
    const int xcd = bid & 7, idx = bid >> 3;
    const int mt = xcd * 16 + (idx & 15), nt = idx >> 4;
    const int mBase = mt * 128, nBase = nt * 256;   // nBase in concat [0,4096)

    const int t = threadIdx.x;
    const int lane = t & 63, wid = t >> 6;          // 4 waves; wid = n-chunk
    const int l31 = lane & 31, hi = lane >> 5;

    // staging: lane l stages row (i*32 + wid*8 + (l>>3)), global chunk (l&7)^(l>>3)
    const int srow   = lane >> 3;
    const int schunk = (lane & 7) ^ srow;

    const uint16_t* Ag = h1t + (size_t)(mBase + wid * 8 + srow) * D_ + schunk * 8;
    const uint16_t* Bg = Bcw + (size_t)h * (4096 * (size_t)D_)
                             + (size_t)(nBase + wid * 8 + srow) * D_ + schunk * 8;

    floatx16 acc[4][2];
#pragma unroll
    for (int mi = 0; mi < 4; mi++)
#pragma unroll
        for (int nj = 0; nj < 2; nj++)
#pragma unroll
            for (int e = 0; e < 16; e++) acc[mi][nj][e] = 0.f;

    const int x7 = l31 & 7;

    for (int kt = 0; kt < D_; kt += 64) {
        // ---- stage A (16 KB) + B (32 KB), linear dest, pre-swizzled source
#pragma unroll
        for (int i = 0; i < 4; i++)
            async16(Ag + (size_t)(i * 32) * D_ + kt, smem + i * 256 + wid * 64);
#pragma unroll
        for (int i = 0; i < 8; i++)
            async16(Bg + (size_t)(i * 32) * D_ + kt, smem + 1024 + i * 256 + wid * 64);
        asm volatile("s_waitcnt vmcnt(0)" ::: "memory");
        __builtin_amdgcn_sched_barrier(0);
        __builtin_amdgcn_s_barrier();

        // ---- compute: 4 k-steps of K=16, 8 MFMAs each
        __builtin_amdgcn_s_setprio(1);
#pragma unroll
        for (int kk = 0; kk < 4; kk++) {
            const int cx = (kk * 2 + hi) ^ x7;
            short8 af[4], bf[2];
#pragma unroll
            for (int mi = 0; mi < 4; mi++)
                af[mi] = bc8(smem[(mi * 32 + l31) * 8 + cx]);
#pragma unroll
            for (int nj = 0; nj < 2; nj++)
                bf[nj] = bc8(smem[1024 + (wid * 64 + nj * 32 + l31) * 8 + cx]);
#pragma unroll
            for (int mi = 0; mi < 4; mi++)
#pragma unroll
                for (int nj = 0; nj < 2; nj++)
                    acc[mi][nj] = __builtin_amdgcn_mfma_f32_32x32x16_bf16(
                        af[mi], bf[nj], acc[mi][nj], 0, 0, 0);
        }
        __builtin_amdgcn_s_setprio(0);
        __syncthreads();   // reads drained before next stage overwrites
    }

    // ---- Epilogue: bias + relu + (.)@W3[half] reduce over n, shuffle, atomics
    const int p    = nBase >> 11;          // 0: W21/W31 path, 1: W22/W32 path
    const int nloc = nBase & 2047;
    const float* b2p = (p ? b22 : b21) + (size_t)h * D_;
    const float* W3p = (p ? W32 : W31) + (size_t)h * D_ * C_;
    float* ab = (p ? acc32 : acc31) + (size_t)h * B_ * C_;

    float bs[2], w3x[2], w3y[2];
#pragma unroll
    for (int nj = 0; nj < 2; nj++) {
        const int e = nloc + wid * 64 + nj * 32 + l31;
        bs[nj] = b2p[e];
        const float2 w2 = *(const float2*)(W3p + e * 2);
        w3x[nj] = w2.x; w3y[nj] = w2.y;
    }
#pragma unroll
    for (int mi = 0; mi < 4; mi++)
#pragma unroll
        for (int r = 0; r < 16; r++) {
            const float v0 = fmaxf(acc[mi][0][r] + bs[0], 0.f);
            const float v1 = fmaxf(acc[mi][1][r] + bs[1], 0.f);
            float s0 = fmaf(v0, w3x[0], v1 * w3x[1]);
            float s1 = fmaf(v0, w3y[0], v1 * w3y[1]);
#pragma unroll
            for (int off = 1; off < 32; off <<= 1) {
                s0 += __shfl_xor(s0, off, 64);
                s1 += __shfl_xor(s1, off, 64);
            }
            if (l31 == 0) {
                const int row = mBase + mi * 32 + (r & 3) + 8 * (r >> 2) + 4 * hi;
                atomicAdd(&ab[row * C_ + 0], s0);
                atomicAdd(&ab[row * C_ + 1], s1);
            }
        }
}

// ---------------------------------------------------------------------------
// Finalize: biases, sigmoid head, CBF-QP correction, softmax-weighted mix
// ---------------------------------------------------------------------------
__global__ __launch_bounds__(256) void k_final(
    const float* __restrict__ x,
    const float* __restrict__ acc31, const float* __restrict__ acc32,
    const float* __restrict__ b31, const float* __restrict__ b32,
    const float* __restrict__ wt, const float* __restrict__ mean,
    const float* __restrict__ stdv, float* __restrict__ out)
{
    const int b = blockIdx.x * 256 + threadIdx.x;
    const float4 xb = *(const float4*)(x + (size_t)b * 4);
    const float px = xb.x * stdv[0] + mean[0];
    const float py = xb.y * stdv[1] + mean[1];
    const float th = xb.z * stdv[2] + mean[2];
    const float v  = xb.w * stdv[3] + mean[3];
    const float dx = px - 40.0f, dy = py - 15.0f;
    const float st = sinf(th), ct = cosf(th);
    const float barrier = dx * dx + dy * dy - 36.0f;
    const float bdot = 2.f * dx * v * ct + 2.f * dy * v * st;
    const float Lf2b = 2.f * v * v;
    const float G0 = -(-2.f * dx * v * st + 2.f * dy * v * ct);
    const float G1 = -(2.f * dx * ct + 2.f * dy * st);
    const float GG = G0 * G0 + G1 * G1;

    float we[H_];
    float wmax = wt[0];
    for (int h = 1; h < H_; h++) wmax = fmaxf(wmax, wt[h]);
    float wsum = 0.f;
    for (int h = 0; h < H_; h++) { we[h] = expf(wt[h] - wmax); wsum += we[h]; }

    float o0 = 0.f, o1 = 0.f;
#pragma unroll
    for (int h = 0; h < H_; h++) {
        const size_t idx = ((size_t)h * B_ + b) * 2;
        const float x310 = acc31[idx]     + b31[h * 2];
        const float x311 = acc31[idx + 1] + b31[h * 2 + 1];
        const float z0 = acc32[idx]     + b32[h * 2];
        const float z1 = acc32[idx + 1] + b32[h * 2 + 1];
        const float x320 = 4.f / (1.f + expf(-z0));
        const float x321 = 4.f / (1.f + expf(-z1));
        const float hr = Lf2b + (x320 + x321) * bdot + x320 * x321 * barrier;
        const float Gu = G0 * x310 + G1 * x311;
        const float lam = fmaxf(Gu - hr, 0.f) / GG;
        o0 += we[h] * (x310 - lam * G0);
        o1 += we[h] * (x311 - lam * G1);
    }
    out[b * 2]     = o0 / wsum;
    out[b * 2 + 1] = o1 / wsum;
}

extern "C" void kernel_launch(void* const* d_in, const int* in_sizes, int n_in,
                              void* d_out, int out_size, void* d_ws, size_t ws_size,
                              hipStream_t stream)
{
    const float* x    = (const float*)d_in[0];
    const float* W1   = (const float*)d_in[1];
    const float* b1   = (const float*)d_in[2];
    const float* W21  = (const float*)d_in[3];
    const float* b21  = (const float*)d_in[4];
    const float* W22  = (const float*)d_in[5];
    const float* b22  = (const float*)d_in[6];
    const float* W31  = (const float*)d_in[7];
    const float* b31  = (const float*)d_in[8];
    const float* W32  = (const float*)d_in[9];
    const float* b32  = (const float*)d_in[10];
    const float* wt   = (const float*)d_in[11];
    const float* mean = (const float*)d_in[12];
    const float* stdv = (const float*)d_in[13];
    float* out = (float*)d_out;

    char* ws = (char*)d_ws;
    uint16_t* Bc   = (uint16_t*)(ws);
    float* acc31   = (float*)(ws + 167772160);
    float* acc32   = (float*)(ws + 169082880);
    uint16_t* h1t  = (uint16_t*)(ws + 170393600);

    k_convert<<<dim3(32, 32, 20), 256, 0, stream>>>(W21, W22, Bc);
    k_zero<<<dim3(640), 256, 0, stream>>>((uint4*)acc31, 163840);
    for (int h = 0; h < H_; ++h) {
        k_h1<<<dim3(1024), 256, 0, stream>>>(x, W1, b1, h1t, h);
        k_gemm<<<dim3(2048), 256, 0, stream>>>(h1t, Bc, b21, b22, W31, W32,
                                               acc31, acc32, h);
    }
    k_final<<<dim3(64), 256, 0, stream>>>(x, acc31, acc32, b31, b32, wt, mean, stdv, out);
}